// Round 4
// baseline (1004.423 us; speedup 1.0000x reference)
//
#include <hip/hip_runtime.h>
#include <math.h>

static constexpr int N_NODES = 100000;
static constexpr int N_EDGES = 1600000;
static constexpr int E_TOT   = N_NODES + N_EDGES;   // edges + self-loops
static constexpr int D   = 512;
static constexpr int FIN = 182;
static constexpr int K1P = 192;                     // FIN padded to mult of 32
static constexpr int M_PAD = 100096;                // 782 * 128
static constexpr float NEG_SLOPE = 0.2f;
static constexpr float LN_EPS = 1e-5f;

typedef __attribute__((ext_vector_type(8))) short short8;
typedef __attribute__((ext_vector_type(4))) float floatx4;
typedef __attribute__((ext_vector_type(2))) float floatx2;

// ---------------- bf16 helpers (storage type: unsigned short) ----------------
__device__ __forceinline__ unsigned short f2bf(float f) {
  unsigned int x = __builtin_bit_cast(unsigned int, f);
  x += 0x7fffu + ((x >> 16) & 1u);   // round-to-nearest-even
  return (unsigned short)(x >> 16);
}
__device__ __forceinline__ void unpack2(unsigned int w, float& lo, float& hi) {
  lo = __builtin_bit_cast(float, w << 16);
  hi = __builtin_bit_cast(float, w & 0xffff0000u);
}

// async global->LDS, 16B per lane; LDS dest = wave-uniform base + lane*16
typedef __attribute__((address_space(1))) const void gv_t;
typedef __attribute__((address_space(3))) void lv_t;
__device__ __forceinline__ void gll16(const void* g, void* l) {
  __builtin_amdgcn_global_load_lds((gv_t*)g, (lv_t*)l, 16, 0, 0);
}

// ---------------------------------------------------------------------------
// init (deg zero + counter) with fused edge-index dtype probe (block 0)
// ---------------------------------------------------------------------------
__global__ __launch_bounds__(256) void k_init(const int* __restrict__ ei,
                                              int* __restrict__ deg,
                                              int* __restrict__ counter,
                                              int* __restrict__ flag) {
  int i = blockIdx.x * 256 + threadIdx.x;
  if (i < N_NODES) deg[i] = 0;
  if (blockIdx.x == 0) {
    bool nz = false;
#pragma unroll
    for (int rp = 0; rp < 8; ++rp) {
      int j = threadIdx.x + rp * 256;          // sample edges 0..2047
      nz |= (ei[2 * j + 1] != 0);
    }
    __shared__ int sh[4];
    int wv = threadIdx.x >> 6;
    if ((threadIdx.x & 63) == 0) sh[wv] = 0;
    __syncthreads();
    if (__any(nz) && (threadIdx.x & 63) == 0) sh[wv] = 1;
    __syncthreads();
    if (threadIdx.x == 0) {
      *flag = sh[0] | sh[1] | sh[2] | sh[3];
      *counter = 0;
    }
  }
}

__device__ __forceinline__ int edge_src(const int* ei, int f, int i) {
  return f ? ei[i] : ei[2 * i];
}
__device__ __forceinline__ int edge_dst(const int* ei, int f, int i) {
  return f ? ei[N_EDGES + i] : ei[2 * (N_EDGES + i)];
}

// ---------------------------------------------------------------------------
// CSR build grouped by dst (range order irrelevant -> atomic range alloc)
// ---------------------------------------------------------------------------
__global__ __launch_bounds__(256) void k_count(const int* __restrict__ ei,
                                               const int* __restrict__ flag,
                                               int* __restrict__ deg) {
  int i = blockIdx.x * 256 + threadIdx.x;
  if (i >= E_TOT) return;
  int f = *flag;
  int d = (i < N_EDGES) ? edge_dst(ei, f, i) : (i - N_EDGES);
  atomicAdd(deg + d, 1);
}

__global__ __launch_bounds__(256) void k_alloc(const int* __restrict__ deg,
                                               int* __restrict__ off,
                                               int* __restrict__ pos,
                                               int* __restrict__ counter) {
  int i = blockIdx.x * 256 + threadIdx.x;
  if (i >= N_NODES) return;
  int r = atomicAdd(counter, deg[i]);
  off[i] = r;
  pos[i] = r;
}

__global__ __launch_bounds__(256) void k_fill(const int* __restrict__ ei,
                                              const int* __restrict__ flag,
                                              int* __restrict__ pos,
                                              int* __restrict__ csr_src) {
  int i = blockIdx.x * 256 + threadIdx.x;
  if (i >= E_TOT) return;
  int f = *flag;
  int s, d;
  if (i < N_EDGES) { s = edge_src(ei, f, i); d = edge_dst(ei, f, i); }
  else             { s = d = i - N_EDGES; }
  int slot = atomicAdd(pos + d, 1);
  csr_src[slot] = s;
}

// ---------------------------------------------------------------------------
// conversion kernels (one-shot, tiny)
// ---------------------------------------------------------------------------
__global__ __launch_bounds__(256) void k_cvt_x(const float* __restrict__ x,
                                               unsigned short* __restrict__ xb) {
  int i = blockIdx.x * 256 + threadIdx.x;
  if (i >= N_NODES * K1P) return;
  int row = i / K1P, col = i - row * K1P;
  float v = (col < FIN) ? x[(size_t)row * FIN + col] : 0.f;
  xb[i] = f2bf(v);
}

__global__ __launch_bounds__(256) void k_cvt_wt(const float* __restrict__ W,
                                                unsigned short* __restrict__ Wt,
                                                int K, int Kpad) {
  int i = blockIdx.x * 256 + threadIdx.x;
  if (i >= 512 * Kpad) return;
  int n = i / Kpad, k = i - n * Kpad;
  Wt[i] = f2bf(k < K ? W[(size_t)k * 512 + n] : 0.f);
}

// out[n,0:2] initialized to bc2 (atomic accumulation target for gemm_cls)
__global__ __launch_bounds__(256) void k_out_init(const float* __restrict__ bc2,
                                                  float* __restrict__ out) {
  int i = blockIdx.x * 256 + threadIdx.x;
  if (i < N_NODES) {
    float2 v; v.x = bc2[0]; v.y = bc2[1];
    ((float2*)out)[i] = v;
  }
}

// ---------------------------------------------------------------------------
// Fused GEMM + sdots (round-1 proven): h = A @ Bt^T per-block as one full head
// (blockIdx.x == head, 128 rows x 128 cols). Epilogue computes in-block the
// s_src/s_dst dots, per-(node,head) absmax, and excess-128 int8 quantization.
//
// h8 row layout (permuted, per head block of 128 bytes): byte at local
// offset o encodes col (o&64) + 16*(o&3) + ((o>>2)&15). k_aggregate decodes
// with the matching compile-time index map.
// ---------------------------------------------------------------------------
__global__ __launch_bounds__(256)
void gemm_fused(const unsigned short* __restrict__ A,
                const unsigned short* __restrict__ Bt,
                const float* __restrict__ a_src,
                const float* __restrict__ a_dst,
                float2* __restrict__ ssc,
                float* __restrict__ s_dst,
                unsigned char* __restrict__ h8,
                int lda)
{
  __shared__ unsigned short As[128 * 32];   // [m][k] 8 KB (reused as sred)
  __shared__ unsigned short Bs[128 * 32];   // [n][k] 8 KB (reused as qscl)
  const int t    = threadIdx.x;
  const int w    = t >> 6;
  const int lane = t & 63;
  const int r    = lane & 15;
  const int q    = lane >> 4;
  const int bm   = blockIdx.y * 128;
  const int bn   = blockIdx.x * 128;        // bn/128 == head
  const int wm   = (w >> 1) * 64;
  const int wn   = (w & 1) * 64;

  const int ch0 = (w * 2 + 0) * 64 + lane;
  const int ch1 = (w * 2 + 1) * 64 + lane;
  const unsigned short* gA0 = A + (size_t)(bm + (ch0 >> 2)) * lda + (ch0 & 3) * 8;
  const unsigned short* gA1 = A + (size_t)(bm + (ch1 >> 2)) * lda + (ch1 & 3) * 8;
  const unsigned short* gB0 = Bt + (size_t)(bn + (ch0 >> 2)) * lda + (ch0 & 3) * 8;
  const unsigned short* gB1 = Bt + (size_t)(bn + (ch1 >> 2)) * lda + (ch1 & 3) * 8;
  unsigned short* lA0 = As + (w * 2 + 0) * 512;
  unsigned short* lA1 = As + (w * 2 + 1) * 512;
  unsigned short* lB0 = Bs + (w * 2 + 0) * 512;
  unsigned short* lB1 = Bs + (w * 2 + 1) * 512;

  floatx4 acc[4][4] = {};

  for (int k0 = 0; k0 < lda; k0 += 32) {
    gll16(gA0 + k0, lA0);
    gll16(gA1 + k0, lA1);
    gll16(gB0 + k0, lB0);
    gll16(gB1 + k0, lB1);
    __syncthreads();

    short8 af[4], bfr[4];
#pragma unroll
    for (int im = 0; im < 4; ++im)
      af[im] = *(const short8*)(As + (wm + im * 16 + r) * 32 + q * 8);
#pragma unroll
    for (int in = 0; in < 4; ++in)
      bfr[in] = *(const short8*)(Bs + (wn + in * 16 + r) * 32 + q * 8);
#pragma unroll
    for (int im = 0; im < 4; ++im)
#pragma unroll
      for (int in = 0; in < 4; ++in)
        acc[im][in] = __builtin_amdgcn_mfma_f32_16x16x32_bf16(
            af[im], bfr[in], acc[im][in], 0, 0, 0);
    __syncthreads();
  }

  // ---- fused sdots epilogue ----
  // C/D layout: local row lr = wm + im*16 + q*4 + rr, local col c = wn + in*16 + r
  float* sred = (float*)As;     // [4 waves][64 rows][4: s_src, s_dst, absmax, pad]
  float* qscl = (float*)Bs;     // [128 rows]

  float asv[4], adv[4];
#pragma unroll
  for (int in = 0; in < 4; ++in) {
    asv[in] = a_src[bn + wn + in * 16 + r];
    adv[in] = a_dst[bn + wn + in * 16 + r];
  }
#pragma unroll
  for (int im = 0; im < 4; ++im) {
    float ps_[4], pd_[4], pm_[4];
#pragma unroll
    for (int rr = 0; rr < 4; ++rr) {
      float s = 0.f, d = 0.f, m = 0.f;
#pragma unroll
      for (int in = 0; in < 4; ++in) {
        float v = acc[im][in][rr];
        s += v * asv[in];
        d += v * adv[in];
        m = fmaxf(m, fabsf(v));
      }
      ps_[rr] = s; pd_[rr] = d; pm_[rr] = m;
    }
#pragma unroll
    for (int o2 = 1; o2 < 16; o2 <<= 1) {
#pragma unroll
      for (int rr = 0; rr < 4; ++rr) {
        ps_[rr] += __shfl_xor(ps_[rr], o2);
        pd_[rr] += __shfl_xor(pd_[rr], o2);
        pm_[rr] = fmaxf(pm_[rr], __shfl_xor(pm_[rr], o2));
      }
    }
    if (r == 0) {
#pragma unroll
      for (int rr = 0; rr < 4; ++rr) {
        int r64 = im * 16 + q * 4 + rr;
        sred[(w * 64 + r64) * 4 + 0] = ps_[rr];
        sred[(w * 64 + r64) * 4 + 1] = pd_[rr];
        sred[(w * 64 + r64) * 4 + 2] = pm_[rr];
      }
    }
  }
  __syncthreads();

  if (t < 128) {
    int hf = t >> 6;                 // which wave pair (row half)
    int r64 = t & 63;
    const float* pa = sred + ((hf * 2 + 0) * 64 + r64) * 4;
    const float* pb = sred + ((hf * 2 + 1) * 64 + r64) * 4;
    float s  = pa[0] + pb[0];
    float dd = pa[1] + pb[1];
    float am = fmaxf(fmaxf(pa[2], pb[2]), 1e-20f);
    qscl[t] = 127.f / am;
    int node = bm + t;
    if (node < N_NODES) {
      float2 sc; sc.x = s; sc.y = am * (1.f / 127.f);
      ssc[(size_t)node * 4 + blockIdx.x] = sc;
      s_dst[(size_t)node * 4 + blockIdx.x] = dd;
    }
  }
  __syncthreads();

  // quantize + pack: dword at local offset wn+4r of row lr holds cols
  // {wn + 16*j + r : j=0..3} in bytes 0..3 (permuted layout, see header).
#pragma unroll
  for (int im = 0; im < 4; ++im) {
#pragma unroll
    for (int rr = 0; rr < 4; ++rr) {
      int lr = wm + im * 16 + q * 4 + rr;
      float qs = qscl[lr];
      unsigned int pk = 0;
#pragma unroll
      for (int in = 0; in < 4; ++in) {
        int qv = (int)rintf(acc[im][in][rr] * qs) + 128;
        pk |= (unsigned int)(qv & 255) << (8 * in);
      }
      *(unsigned int*)(h8 + (size_t)(bm + lr) * 512 + bn + wn + 4 * r) = pk;
    }
  }
}

// ---------------------------------------------------------------------------
// Classifier GEMM with fused relu(z)@Wc2 epilogue (round-8 proven)
// ---------------------------------------------------------------------------
__global__ __launch_bounds__(256)
void gemm_cls(const unsigned short* __restrict__ A,
              const unsigned short* __restrict__ Bt,
              const float* __restrict__ bc1,
              const float* __restrict__ Wc2,
              float* __restrict__ out,
              int lda)
{
  __shared__ unsigned short As[128 * 32];
  __shared__ unsigned short Bs[128 * 32];
  const int t    = threadIdx.x;
  const int w    = t >> 6;
  const int lane = t & 63;
  const int r    = lane & 15;
  const int q    = lane >> 4;
  const int bm   = blockIdx.y * 128;
  const int bn   = blockIdx.x * 128;
  const int wm   = (w >> 1) * 64;
  const int wn   = (w & 1) * 64;

  const int ch0 = (w * 2 + 0) * 64 + lane;
  const int ch1 = (w * 2 + 1) * 64 + lane;
  const unsigned short* gA0 = A + (size_t)(bm + (ch0 >> 2)) * lda + (ch0 & 3) * 8;
  const unsigned short* gA1 = A + (size_t)(bm + (ch1 >> 2)) * lda + (ch1 & 3) * 8;
  const unsigned short* gB0 = Bt + (size_t)(bn + (ch0 >> 2)) * lda + (ch0 & 3) * 8;
  const unsigned short* gB1 = Bt + (size_t)(bn + (ch1 >> 2)) * lda + (ch1 & 3) * 8;
  unsigned short* lA0 = As + (w * 2 + 0) * 512;
  unsigned short* lA1 = As + (w * 2 + 1) * 512;
  unsigned short* lB0 = Bs + (w * 2 + 0) * 512;
  unsigned short* lB1 = Bs + (w * 2 + 1) * 512;

  floatx4 acc[4][4] = {};

  for (int k0 = 0; k0 < lda; k0 += 32) {
    gll16(gA0 + k0, lA0);
    gll16(gA1 + k0, lA1);
    gll16(gB0 + k0, lB0);
    gll16(gB1 + k0, lB1);
    __syncthreads();

    short8 af[4], bfr[4];
#pragma unroll
    for (int im = 0; im < 4; ++im)
      af[im] = *(const short8*)(As + (wm + im * 16 + r) * 32 + q * 8);
#pragma unroll
    for (int in = 0; in < 4; ++in)
      bfr[in] = *(const short8*)(Bs + (wn + in * 16 + r) * 32 + q * 8);
#pragma unroll
    for (int im = 0; im < 4; ++im)
#pragma unroll
      for (int in = 0; in < 4; ++in)
        acc[im][in] = __builtin_amdgcn_mfma_f32_16x16x32_bf16(
            af[im], bfr[in], acc[im][in], 0, 0, 0);
    __syncthreads();
  }

  float p0[16], p1[16];   // [im*4+rr] -> row bm+wm+im*16+q*4+rr
#pragma unroll
  for (int k = 0; k < 16; ++k) { p0[k] = 0.f; p1[k] = 0.f; }

#pragma unroll
  for (int in = 0; in < 4; ++in) {
    const int col = bn + wn + in * 16 + r;
    const float bv = bc1[col];
    const float w0 = Wc2[col * 2 + 0];
    const float w1 = Wc2[col * 2 + 1];
#pragma unroll
    for (int im = 0; im < 4; ++im)
#pragma unroll
      for (int rr = 0; rr < 4; ++rr) {
        float z = fmaxf(acc[im][in][rr] + bv, 0.f);
        p0[im * 4 + rr] += z * w0;
        p1[im * 4 + rr] += z * w1;
      }
  }
#pragma unroll
  for (int o2 = 1; o2 < 16; o2 <<= 1) {
#pragma unroll
    for (int k = 0; k < 16; ++k) {
      p0[k] += __shfl_xor(p0[k], o2);
      p1[k] += __shfl_xor(p1[k], o2);
    }
  }
  if (r == 0) {
#pragma unroll
    for (int im = 0; im < 4; ++im)
#pragma unroll
      for (int rr = 0; rr < 4; ++rr) {
        int row = bm + wm + im * 16 + q * 4 + rr;
        if (row < N_NODES) {
          atomicAdd(out + (size_t)row * 2,     p0[im * 4 + rr]);
          atomicAdd(out + (size_t)row * 2 + 1, p1[im * 4 + rr]);
        }
      }
  }
}

// ---------------------------------------------------------------------------
// Fused segment-softmax + aggregation + bias + LayerNorm + ELU.
// Round-4 change: 2-deep ping-pong software pipeline over 16-edge chunks.
// Issue chunk c+1's 16 h8-row loads (into the other register buffer) BEFORE
// accumulating chunk c, so for the typical node (deg ~17 = one chunk + tail)
// ALL row loads are in flight before the first accumulate -- one gather
// latency window per node instead of two. Full chunks use branch-free
// bodies; partial chunks use wave-uniform predication with compile-time
// indices (no scratch). Numerics identical to round 3.
// h8 decode mapping identical to round 1 (channel = cbase + 16*(k&3)+(k>>2)).
// ---------------------------------------------------------------------------
#define AGG_ISSUE_F(ROWS, FC, BASE)                                         \
  do {                                                                      \
    int srcl_ = csr_src[o + (BASE) + li];                                   \
    FC = ssc[(size_t)srcl_ * 4 + head];                                     \
    _Pragma("unroll")                                                       \
    for (int j = 0; j < 16; ++j) {                                          \
      int sj_ = __builtin_amdgcn_readlane(srcl_, j);                        \
      ROWS[j] = *(const uint2*)(h8 + (size_t)sj_ * 512 + lane * 8);         \
    }                                                                       \
  } while (0)

#define AGG_ISSUE_P(ROWS, FC, BASE, M)                                      \
  do {                                                                      \
    int idx_ = (li < (M)) ? li : ((M) - 1);                                 \
    int srcl_ = csr_src[o + (BASE) + idx_];                                 \
    FC = ssc[(size_t)srcl_ * 4 + head];                                     \
    _Pragma("unroll")                                                       \
    for (int j = 0; j < 16; ++j) {                                          \
      if (j < (M)) {                                                        \
        int sj_ = __builtin_amdgcn_readlane(srcl_, j);                      \
        ROWS[j] = *(const uint2*)(h8 + (size_t)sj_ * 512 + lane * 8);       \
      }                                                                     \
    }                                                                       \
  } while (0)

#define AGG_BODY(WREG, PSJ)                                                 \
  do {                                                                      \
    uint2 w_ = (WREG);                                                      \
    floatx2 vp_ = {(PSJ), (PSJ)};                                           \
    floatx2 b0_ = {(float)( w_.x        & 255u), (float)( w_.y        & 255u)}; \
    floatx2 b1_ = {(float)((w_.x >>  8) & 255u), (float)((w_.y >>  8) & 255u)}; \
    floatx2 b2_ = {(float)((w_.x >> 16) & 255u), (float)((w_.y >> 16) & 255u)}; \
    floatx2 b3_ = {(float)( w_.x >> 24        ), (float)( w_.y >> 24        )}; \
    acc2[0] += vp_ * b0_;                                                   \
    acc2[1] += vp_ * b1_;                                                   \
    acc2[2] += vp_ * b2_;                                                   \
    acc2[3] += vp_ * b3_;                                                   \
  } while (0)

#define AGG_ACCUM_F(ROWS, FC)                                               \
  do {                                                                      \
    float e_ = FC.x + sdH;                                                  \
    e_ = (e_ > 0.f) ? e_ : NEG_SLOPE * e_;                                  \
    float p_ = __expf(e_);                                                  \
    float ps_ = p_ * FC.y;                                                  \
    sumP += p_; sumPS += ps_;                                               \
    _Pragma("unroll")                                                       \
    for (int j = 0; j < 16; ++j) {                                          \
      float psj_ = __shfl(ps_, j, 16);                                      \
      AGG_BODY(ROWS[j], psj_);                                              \
    }                                                                       \
  } while (0)

#define AGG_ACCUM_P(ROWS, FC, M)                                            \
  do {                                                                      \
    float e_ = FC.x + sdH;                                                  \
    e_ = (e_ > 0.f) ? e_ : NEG_SLOPE * e_;                                  \
    float p_ = (li < (M)) ? __expf(e_) : 0.f;                               \
    float ps_ = p_ * FC.y;                                                  \
    sumP += p_; sumPS += ps_;                                               \
    _Pragma("unroll")                                                       \
    for (int j = 0; j < 16; ++j) {                                          \
      if (j < (M)) {                                                        \
        float psj_ = __shfl(ps_, j, 16);                                    \
        AGG_BODY(ROWS[j], psj_);                                            \
      }                                                                     \
    }                                                                       \
  } while (0)

__global__ __launch_bounds__(256) void k_aggregate(const unsigned char* __restrict__ h8,
                                                   const float2* __restrict__ ssc,
                                                   const int* __restrict__ csr_src,
                                                   const int* __restrict__ off,
                                                   const int* __restrict__ deg,
                                                   const float* __restrict__ s_dst,
                                                   const float* __restrict__ bvec,
                                                   const float* __restrict__ gvec,
                                                   const float* __restrict__ bevec,
                                                   unsigned short* __restrict__ out) {
  int node = blockIdx.x * 4 + (threadIdx.x >> 6);
  int lane = threadIdx.x & 63;
  if (node >= N_NODES) return;
  const int o   = __builtin_amdgcn_readfirstlane(off[node]);
  const int cnt = __builtin_amdgcn_readfirstlane(deg[node]);
  const int head = lane >> 4;
  const int li   = lane & 15;
  const int cbase = head * 128 + ((li & 8) ? 64 : 0) + ((2 * li) & 15);
  const float sdH = s_dst[(size_t)node * 4 + head];

  // acc2[k] = (channel cbase+16k [wx byte k], channel cbase+16k+1 [wy byte k])
  floatx2 acc2[4] = {};
  float sumP = 0.f, sumPS = 0.f;

  uint2 rowsA[16], rowsB[16];
  float2 fcA, fcB;

  // ---- 2-deep ping-pong pipeline over 16-edge chunks (cnt >= 1 always) ----
  int base = 0;
  int mA = (cnt < 16) ? cnt : 16;
  if (mA == 16) AGG_ISSUE_F(rowsA, fcA, 0);
  else          AGG_ISSUE_P(rowsA, fcA, 0, mA);
  base = mA;
  int rem = cnt - base;
  int mB = (rem < 16) ? rem : 16;
  if (mB == 16)     AGG_ISSUE_F(rowsB, fcB, base);
  else if (mB > 0)  AGG_ISSUE_P(rowsB, fcB, base, mB);
  base += mB;

  for (;;) {
    if (mA == 16) AGG_ACCUM_F(rowsA, fcA);
    else          AGG_ACCUM_P(rowsA, fcA, mA);
    if (mB == 0) break;
    rem = cnt - base;
    mA = (rem < 16) ? rem : 16;
    if (mA == 16)    { AGG_ISSUE_F(rowsA, fcA, base); base += 16; }
    else if (mA > 0) { AGG_ISSUE_P(rowsA, fcA, base, mA); base += mA; }
    if (mB == 16) AGG_ACCUM_F(rowsB, fcB);
    else          AGG_ACCUM_P(rowsB, fcB, mB);
    if (mA == 0) break;
    rem = cnt - base;
    mB = (rem < 16) ? rem : 16;
    if (mB == 16)    { AGG_ISSUE_F(rowsB, fcB, base); base += 16; }
    else if (mB > 0) { AGG_ISSUE_P(rowsB, fcB, base, mB); base += mB; }
  }

  // reduce per-lane score partials across the 16-lane head group
#pragma unroll
  for (int o2 = 1; o2 < 16; o2 <<= 1) {
    sumP  += __shfl_xor(sumP,  o2);
    sumPS += __shfl_xor(sumPS, o2);
  }

  float acc[8];
#pragma unroll
  for (int k = 0; k < 4; ++k) { acc[k] = acc2[k].x; acc[k + 4] = acc2[k].y; }

  const float inv = 1.f / sumP;
  float bl[8];
#pragma unroll
  for (int k = 0; k < 4; ++k) {
    float2 v2 = *(const float2*)(bvec + cbase + 16 * k);
    bl[k] = v2.x; bl[k + 4] = v2.y;
  }
#pragma unroll
  for (int k = 0; k < 8; ++k)
    acc[k] = (acc[k] - 128.f * sumPS) * inv + bl[k];

  float ps2 = 0.f, pq = 0.f;
#pragma unroll
  for (int k = 0; k < 8; ++k) { ps2 += acc[k]; pq += acc[k]*acc[k]; }
#pragma unroll
  for (int o2 = 1; o2 < 64; o2 <<= 1) {
    ps2 += __shfl_xor(ps2, o2);
    pq  += __shfl_xor(pq, o2);
  }
  float mu  = ps2 * (1.f/512.f);
  float var = pq * (1.f/512.f) - mu*mu;
  float rstd = rsqrtf(var + LN_EPS);

  float gs[8], es[8];
#pragma unroll
  for (int k = 0; k < 4; ++k) {
    float2 g2 = *(const float2*)(gvec  + cbase + 16 * k);
    float2 e2 = *(const float2*)(bevec + cbase + 16 * k);
    gs[k] = g2.x; gs[k + 4] = g2.y;
    es[k] = e2.x; es[k + 4] = e2.y;
  }

  unsigned short us[8];
#pragma unroll
  for (int k = 0; k < 8; ++k) {
    float y = (acc[k] - mu) * rstd * gs[k] + es[k];
    y = (y > 0.f) ? y : expm1f(y);
    us[k] = f2bf(y);
  }
#pragma unroll
  for (int k = 0; k < 4; ++k) {
    unsigned int wv2 = (unsigned int)us[k] | ((unsigned int)us[k + 4] << 16);
    *(unsigned int*)(out + (size_t)node * D + cbase + 16 * k) = wv2;
  }
}

// ---------------------------------------------------------------------------
extern "C" void kernel_launch(void* const* d_in, const int* in_sizes, int n_in,
                              void* d_out, int out_size, void* d_ws, size_t ws_size,
                              hipStream_t stream) {
  const float* x      = (const float*)d_in[0];
  const int*   ei     = (const int*)  d_in[1];
  const float* W1     = (const float*)d_in[2];
  const float* a_src1 = (const float*)d_in[3];
  const float* a_dst1 = (const float*)d_in[4];
  const float* b1     = (const float*)d_in[5];
  const float* g1     = (const float*)d_in[6];
  const float* be1    = (const float*)d_in[7];
  const float* W2     = (const float*)d_in[8];
  const float* a_src2 = (const float*)d_in[9];
  const float* a_dst2 = (const float*)d_in[10];
  const float* b2     = (const float*)d_in[11];
  const float* g2     = (const float*)d_in[12];
  const float* be2    = (const float*)d_in[13];
  const float* Wc1    = (const float*)d_in[14];
  const float* bc1    = (const float*)d_in[15];
  const float* Wc2    = (const float*)d_in[16];
  const float* bc2    = (const float*)d_in[17];
  float* outp = (float*)d_out;

  char* p = (char*)d_ws;
  auto alloc = [&](size_t bytes) {
    char* r = p;
    p += (bytes + 255) & ~(size_t)255;
    return r;
  };
  unsigned short* obuf = (unsigned short*)alloc((size_t)M_PAD * D * 2); // 102.5 MB
  unsigned short* w1t  = (unsigned short*)alloc((size_t)512 * K1P * 2);
  unsigned short* w2t  = (unsigned short*)alloc((size_t)512 * 512 * 2);
  unsigned short* wc1t = (unsigned short*)alloc((size_t)512 * 512 * 2);
  int*   csr_src = (int*)  alloc((size_t)E_TOT * 4);                    // 6.8 MB
  int*   deg     = (int*)  alloc((size_t)N_NODES * 4);
  int*   off     = (int*)  alloc((size_t)N_NODES * 4);
  int*   pos     = (int*)  alloc((size_t)N_NODES * 4);
  int*   counter = (int*)  alloc(256);
  int*   flag    = (int*)  alloc(256);
  float2* ssc    = (float2*)alloc((size_t)N_NODES * 4 * 8);             // 3.2 MB
  float* s_dst   = (float*)alloc((size_t)N_NODES * 4 * 4);              // 1.6 MB
  unsigned char* h8 = (unsigned char*)alloc((size_t)M_PAD * 512);       // 51.2 MB
  // total ~= 168 MB (hbuf eliminated by the fused GEMM+sdots epilogue)
  // xb aliases obuf (dead after GEMM-1's A-reads, then overwritten by agg-1)
  unsigned short* xb = obuf;

  const int EB = (E_TOT + 255) / 256;
  const int NB = (N_NODES + 255) / 256;
  const int NW = (N_NODES + 3) / 4;
  dim3 gg(4, M_PAD / 128);

  // init (+fused dtype probe) + CSR build + weight conversion
  k_init  <<<NB, 256, 0, stream>>>(ei, deg, counter, flag);
  k_count <<<EB, 256, 0, stream>>>(ei, flag, deg);
  k_alloc <<<NB, 256, 0, stream>>>(deg, off, pos, counter);
  k_fill  <<<EB, 256, 0, stream>>>(ei, flag, pos, csr_src);

  k_cvt_x <<<(N_NODES * K1P + 255) / 256, 256, 0, stream>>>(x, xb);
  k_cvt_wt<<<(512 * K1P + 255) / 256, 256, 0, stream>>>(W1, w1t, FIN, K1P);
  k_cvt_wt<<<(512 * 512 + 255) / 256, 256, 0, stream>>>(W2, w2t, 512, 512);
  k_cvt_wt<<<(512 * 512 + 255) / 256, 256, 0, stream>>>(Wc1, wc1t, 512, 512);
  k_out_init<<<NB, 256, 0, stream>>>(bc2, outp);

  // Layer 1 (GEMM writes h8/ssc/s_dst directly; no bf16 h round-trip)
  gemm_fused <<<gg, 256, 0, stream>>>(xb, w1t, a_src1, a_dst1, ssc, s_dst, h8, K1P);
  k_aggregate<<<NW, 256, 0, stream>>>(h8, ssc, csr_src, off, deg,
                                      s_dst, b1, g1, be1, obuf);

  // Layer 2
  gemm_fused <<<gg, 256, 0, stream>>>(obuf, w2t, a_src2, a_dst2, ssc, s_dst, h8, 512);
  k_aggregate<<<NW, 256, 0, stream>>>(h8, ssc, csr_src, off, deg,
                                      s_dst, b2, g2, be2, obuf);

  // Classifier (fused relu + @Wc2 + bc2 via atomics)
  gemm_cls   <<<gg, 256, 0, stream>>>(obuf, wc1t, bc1, Wc2, outp, 512);
}

// Round 5
// 965.568 us; speedup vs baseline: 1.0402x; 1.0402x over previous
//
#include <hip/hip_runtime.h>
#include <math.h>

static constexpr int N_NODES = 100000;
static constexpr int N_EDGES = 1600000;
static constexpr int E_TOT   = N_NODES + N_EDGES;   // edges + self-loops
static constexpr int D   = 512;
static constexpr int FIN = 182;
static constexpr int K1P = 192;                     // FIN padded to mult of 64
static constexpr int M_PAD = 100096;                // 782 * 128
static constexpr float NEG_SLOPE = 0.2f;
static constexpr float LN_EPS = 1e-5f;

typedef __attribute__((ext_vector_type(8))) short short8;
typedef __attribute__((ext_vector_type(4))) float floatx4;
typedef __attribute__((ext_vector_type(2))) float floatx2;

// ---------------- bf16 helpers (storage type: unsigned short) ----------------
__device__ __forceinline__ unsigned short f2bf(float f) {
  unsigned int x = __builtin_bit_cast(unsigned int, f);
  x += 0x7fffu + ((x >> 16) & 1u);   // round-to-nearest-even
  return (unsigned short)(x >> 16);
}
__device__ __forceinline__ void unpack2(unsigned int w, float& lo, float& hi) {
  lo = __builtin_bit_cast(float, w << 16);
  hi = __builtin_bit_cast(float, w & 0xffff0000u);
}

// async global->LDS, 16B per lane; LDS dest = wave-uniform base + lane*16
typedef __attribute__((address_space(1))) const void gv_t;
typedef __attribute__((address_space(3))) void lv_t;
__device__ __forceinline__ void gll16(const void* g, void* l) {
  __builtin_amdgcn_global_load_lds((gv_t*)g, (lv_t*)l, 16, 0, 0);
}

// ---------------------------------------------------------------------------
// init (deg zero + counter) with fused edge-index dtype probe (block 0)
// ---------------------------------------------------------------------------
__global__ __launch_bounds__(256) void k_init(const int* __restrict__ ei,
                                              int* __restrict__ deg,
                                              int* __restrict__ counter,
                                              int* __restrict__ flag) {
  int i = blockIdx.x * 256 + threadIdx.x;
  if (i < N_NODES) deg[i] = 0;
  if (blockIdx.x == 0) {
    bool nz = false;
#pragma unroll
    for (int rp = 0; rp < 8; ++rp) {
      int j = threadIdx.x + rp * 256;          // sample edges 0..2047
      nz |= (ei[2 * j + 1] != 0);
    }
    __shared__ int sh[4];
    int wv = threadIdx.x >> 6;
    if ((threadIdx.x & 63) == 0) sh[wv] = 0;
    __syncthreads();
    if (__any(nz) && (threadIdx.x & 63) == 0) sh[wv] = 1;
    __syncthreads();
    if (threadIdx.x == 0) {
      *flag = sh[0] | sh[1] | sh[2] | sh[3];
      *counter = 0;
    }
  }
}

__device__ __forceinline__ int edge_src(const int* ei, int f, int i) {
  return f ? ei[i] : ei[2 * i];
}
__device__ __forceinline__ int edge_dst(const int* ei, int f, int i) {
  return f ? ei[N_EDGES + i] : ei[2 * (N_EDGES + i)];
}

// ---------------------------------------------------------------------------
// CSR build grouped by dst (range order irrelevant -> atomic range alloc)
// ---------------------------------------------------------------------------
__global__ __launch_bounds__(256) void k_count(const int* __restrict__ ei,
                                               const int* __restrict__ flag,
                                               int* __restrict__ deg) {
  int i = blockIdx.x * 256 + threadIdx.x;
  if (i >= E_TOT) return;
  int f = *flag;
  int d = (i < N_EDGES) ? edge_dst(ei, f, i) : (i - N_EDGES);
  atomicAdd(deg + d, 1);
}

__global__ __launch_bounds__(256) void k_alloc(const int* __restrict__ deg,
                                               int* __restrict__ off,
                                               int* __restrict__ pos,
                                               int* __restrict__ counter) {
  int i = blockIdx.x * 256 + threadIdx.x;
  if (i >= N_NODES) return;
  int r = atomicAdd(counter, deg[i]);
  off[i] = r;
  pos[i] = r;
}

__global__ __launch_bounds__(256) void k_fill(const int* __restrict__ ei,
                                              const int* __restrict__ flag,
                                              int* __restrict__ pos,
                                              int* __restrict__ csr_src) {
  int i = blockIdx.x * 256 + threadIdx.x;
  if (i >= E_TOT) return;
  int f = *flag;
  int s, d;
  if (i < N_EDGES) { s = edge_src(ei, f, i); d = edge_dst(ei, f, i); }
  else             { s = d = i - N_EDGES; }
  int slot = atomicAdd(pos + d, 1);
  csr_src[slot] = s;
}

// ---------------------------------------------------------------------------
// conversion kernels (one-shot, tiny)
// ---------------------------------------------------------------------------
__global__ __launch_bounds__(256) void k_cvt_x(const float* __restrict__ x,
                                               unsigned short* __restrict__ xb) {
  int i = blockIdx.x * 256 + threadIdx.x;
  if (i >= N_NODES * K1P) return;
  int row = i / K1P, col = i - row * K1P;
  float v = (col < FIN) ? x[(size_t)row * FIN + col] : 0.f;
  xb[i] = f2bf(v);
}

__global__ __launch_bounds__(256) void k_cvt_wt(const float* __restrict__ W,
                                                unsigned short* __restrict__ Wt,
                                                int K, int Kpad) {
  int i = blockIdx.x * 256 + threadIdx.x;
  if (i >= 512 * Kpad) return;
  int n = i / Kpad, k = i - n * Kpad;
  Wt[i] = f2bf(k < K ? W[(size_t)k * 512 + n] : 0.f);
}

// out[n,0:2] initialized to bc2 (atomic accumulation target for gemm_cls)
__global__ __launch_bounds__(256) void k_out_init(const float* __restrict__ bc2,
                                                  float* __restrict__ out) {
  int i = blockIdx.x * 256 + threadIdx.x;
  if (i < N_NODES) {
    float2 v; v.x = bc2[0]; v.y = bc2[1];
    ((float2*)out)[i] = v;
  }
}

// ---------------------------------------------------------------------------
// Fused GEMM + sdots: h = A @ Bt^T per-block as one full head (blockIdx.x ==
// head, 128 rows x 128 cols). Round-5 change: BK=64 per barrier pair via TWO
// independent BK=32 LDS buffer sets (identical per-half layout/banking to the
// proven kernel) -- 8 gll16 issues per sync, 32 MFMAs per step, HALF the
// barrier drains of the BK=32 loop. Requires lda % 64 == 0 (192, 512 ok).
// Epilogue (proven round 1): in-block s_src/s_dst dots, per-(node,head)
// absmax, excess-128 int8 quantization.
// h8 row layout (permuted, per head block of 128 bytes): byte at local
// offset o encodes col (o&64) + 16*(o&3) + ((o>>2)&15).
// ---------------------------------------------------------------------------
__global__ __launch_bounds__(256)
void gemm_fused(const unsigned short* __restrict__ A,
                const unsigned short* __restrict__ Bt,
                const float* __restrict__ a_src,
                const float* __restrict__ a_dst,
                float2* __restrict__ ssc,
                float* __restrict__ s_dst,
                unsigned char* __restrict__ h8,
                int lda)
{
  __shared__ unsigned short As[2][128 * 32];   // [half][m][k] 2 x 8 KB
  __shared__ unsigned short Bs[2][128 * 32];   // [half][n][k] 2 x 8 KB
  const int t    = threadIdx.x;
  const int w    = t >> 6;
  const int lane = t & 63;
  const int r    = lane & 15;
  const int q    = lane >> 4;
  const int bm   = blockIdx.y * 128;
  const int bn   = blockIdx.x * 128;        // bn/128 == head
  const int wm   = (w >> 1) * 64;
  const int wn   = (w & 1) * 64;

  const int ch0 = (w * 2 + 0) * 64 + lane;
  const int ch1 = (w * 2 + 1) * 64 + lane;
  const unsigned short* gA0 = A + (size_t)(bm + (ch0 >> 2)) * lda + (ch0 & 3) * 8;
  const unsigned short* gA1 = A + (size_t)(bm + (ch1 >> 2)) * lda + (ch1 & 3) * 8;
  const unsigned short* gB0 = Bt + (size_t)(bn + (ch0 >> 2)) * lda + (ch0 & 3) * 8;
  const unsigned short* gB1 = Bt + (size_t)(bn + (ch1 >> 2)) * lda + (ch1 & 3) * 8;

  floatx4 acc[4][4] = {};

  for (int k0 = 0; k0 < lda; k0 += 64) {
    gll16(gA0 + k0,      &As[0][(w * 2 + 0) * 512]);
    gll16(gA1 + k0,      &As[0][(w * 2 + 1) * 512]);
    gll16(gB0 + k0,      &Bs[0][(w * 2 + 0) * 512]);
    gll16(gB1 + k0,      &Bs[0][(w * 2 + 1) * 512]);
    gll16(gA0 + k0 + 32, &As[1][(w * 2 + 0) * 512]);
    gll16(gA1 + k0 + 32, &As[1][(w * 2 + 1) * 512]);
    gll16(gB0 + k0 + 32, &Bs[1][(w * 2 + 0) * 512]);
    gll16(gB1 + k0 + 32, &Bs[1][(w * 2 + 1) * 512]);
    __syncthreads();

#pragma unroll
    for (int half = 0; half < 2; ++half) {
      short8 af[4], bfr[4];
#pragma unroll
      for (int im = 0; im < 4; ++im)
        af[im] = *(const short8*)(&As[half][(wm + im * 16 + r) * 32 + q * 8]);
#pragma unroll
      for (int in = 0; in < 4; ++in)
        bfr[in] = *(const short8*)(&Bs[half][(wn + in * 16 + r) * 32 + q * 8]);
#pragma unroll
      for (int im = 0; im < 4; ++im)
#pragma unroll
        for (int in = 0; in < 4; ++in)
          acc[im][in] = __builtin_amdgcn_mfma_f32_16x16x32_bf16(
              af[im], bfr[in], acc[im][in], 0, 0, 0);
    }
    __syncthreads();
  }

  // ---- fused sdots epilogue ----
  // C/D layout: local row lr = wm + im*16 + q*4 + rr, local col c = wn + in*16 + r
  float* sred = (float*)&As[0][0]; // [4 waves][64 rows][4: s_src, s_dst, absmax, pad]
  float* qscl = (float*)&Bs[0][0]; // [128 rows]

  float asv[4], adv[4];
#pragma unroll
  for (int in = 0; in < 4; ++in) {
    asv[in] = a_src[bn + wn + in * 16 + r];
    adv[in] = a_dst[bn + wn + in * 16 + r];
  }
#pragma unroll
  for (int im = 0; im < 4; ++im) {
    float ps_[4], pd_[4], pm_[4];
#pragma unroll
    for (int rr = 0; rr < 4; ++rr) {
      float s = 0.f, d = 0.f, m = 0.f;
#pragma unroll
      for (int in = 0; in < 4; ++in) {
        float v = acc[im][in][rr];
        s += v * asv[in];
        d += v * adv[in];
        m = fmaxf(m, fabsf(v));
      }
      ps_[rr] = s; pd_[rr] = d; pm_[rr] = m;
    }
#pragma unroll
    for (int o2 = 1; o2 < 16; o2 <<= 1) {
#pragma unroll
      for (int rr = 0; rr < 4; ++rr) {
        ps_[rr] += __shfl_xor(ps_[rr], o2);
        pd_[rr] += __shfl_xor(pd_[rr], o2);
        pm_[rr] = fmaxf(pm_[rr], __shfl_xor(pm_[rr], o2));
      }
    }
    if (r == 0) {
#pragma unroll
      for (int rr = 0; rr < 4; ++rr) {
        int r64 = im * 16 + q * 4 + rr;
        sred[(w * 64 + r64) * 4 + 0] = ps_[rr];
        sred[(w * 64 + r64) * 4 + 1] = pd_[rr];
        sred[(w * 64 + r64) * 4 + 2] = pm_[rr];
      }
    }
  }
  __syncthreads();

  if (t < 128) {
    int hf = t >> 6;                 // which wave pair (row half)
    int r64 = t & 63;
    const float* pa = sred + ((hf * 2 + 0) * 64 + r64) * 4;
    const float* pb = sred + ((hf * 2 + 1) * 64 + r64) * 4;
    float s  = pa[0] + pb[0];
    float dd = pa[1] + pb[1];
    float am = fmaxf(fmaxf(pa[2], pb[2]), 1e-20f);
    qscl[t] = 127.f / am;
    int node = bm + t;
    if (node < N_NODES) {
      float2 sc; sc.x = s; sc.y = am * (1.f / 127.f);
      ssc[(size_t)node * 4 + blockIdx.x] = sc;
      s_dst[(size_t)node * 4 + blockIdx.x] = dd;
    }
  }
  __syncthreads();

  // quantize + pack: dword at local offset wn+4r of row lr holds cols
  // {wn + 16*j + r : j=0..3} in bytes 0..3 (permuted layout, see header).
#pragma unroll
  for (int im = 0; im < 4; ++im) {
#pragma unroll
    for (int rr = 0; rr < 4; ++rr) {
      int lr = wm + im * 16 + q * 4 + rr;
      float qs = qscl[lr];
      unsigned int pk = 0;
#pragma unroll
      for (int in = 0; in < 4; ++in) {
        int qv = (int)rintf(acc[im][in][rr] * qs) + 128;
        pk |= (unsigned int)(qv & 255) << (8 * in);
      }
      *(unsigned int*)(h8 + (size_t)(bm + lr) * 512 + bn + wn + 4 * r) = pk;
    }
  }
}

// ---------------------------------------------------------------------------
// Classifier GEMM with fused relu(z)@Wc2 epilogue; BK=64 dual-buffer K-loop.
// ---------------------------------------------------------------------------
__global__ __launch_bounds__(256)
void gemm_cls(const unsigned short* __restrict__ A,
              const unsigned short* __restrict__ Bt,
              const float* __restrict__ bc1,
              const float* __restrict__ Wc2,
              float* __restrict__ out,
              int lda)
{
  __shared__ unsigned short As[2][128 * 32];
  __shared__ unsigned short Bs[2][128 * 32];
  const int t    = threadIdx.x;
  const int w    = t >> 6;
  const int lane = t & 63;
  const int r    = lane & 15;
  const int q    = lane >> 4;
  const int bm   = blockIdx.y * 128;
  const int bn   = blockIdx.x * 128;
  const int wm   = (w >> 1) * 64;
  const int wn   = (w & 1) * 64;

  const int ch0 = (w * 2 + 0) * 64 + lane;
  const int ch1 = (w * 2 + 1) * 64 + lane;
  const unsigned short* gA0 = A + (size_t)(bm + (ch0 >> 2)) * lda + (ch0 & 3) * 8;
  const unsigned short* gA1 = A + (size_t)(bm + (ch1 >> 2)) * lda + (ch1 & 3) * 8;
  const unsigned short* gB0 = Bt + (size_t)(bn + (ch0 >> 2)) * lda + (ch0 & 3) * 8;
  const unsigned short* gB1 = Bt + (size_t)(bn + (ch1 >> 2)) * lda + (ch1 & 3) * 8;

  floatx4 acc[4][4] = {};

  for (int k0 = 0; k0 < lda; k0 += 64) {
    gll16(gA0 + k0,      &As[0][(w * 2 + 0) * 512]);
    gll16(gA1 + k0,      &As[0][(w * 2 + 1) * 512]);
    gll16(gB0 + k0,      &Bs[0][(w * 2 + 0) * 512]);
    gll16(gB1 + k0,      &Bs[0][(w * 2 + 1) * 512]);
    gll16(gA0 + k0 + 32, &As[1][(w * 2 + 0) * 512]);
    gll16(gA1 + k0 + 32, &As[1][(w * 2 + 1) * 512]);
    gll16(gB0 + k0 + 32, &Bs[1][(w * 2 + 0) * 512]);
    gll16(gB1 + k0 + 32, &Bs[1][(w * 2 + 1) * 512]);
    __syncthreads();

#pragma unroll
    for (int half = 0; half < 2; ++half) {
      short8 af[4], bfr[4];
#pragma unroll
      for (int im = 0; im < 4; ++im)
        af[im] = *(const short8*)(&As[half][(wm + im * 16 + r) * 32 + q * 8]);
#pragma unroll
      for (int in = 0; in < 4; ++in)
        bfr[in] = *(const short8*)(&Bs[half][(wn + in * 16 + r) * 32 + q * 8]);
#pragma unroll
      for (int im = 0; im < 4; ++im)
#pragma unroll
        for (int in = 0; in < 4; ++in)
          acc[im][in] = __builtin_amdgcn_mfma_f32_16x16x32_bf16(
              af[im], bfr[in], acc[im][in], 0, 0, 0);
    }
    __syncthreads();
  }

  float p0[16], p1[16];   // [im*4+rr] -> row bm+wm+im*16+q*4+rr
#pragma unroll
  for (int k = 0; k < 16; ++k) { p0[k] = 0.f; p1[k] = 0.f; }

#pragma unroll
  for (int in = 0; in < 4; ++in) {
    const int col = bn + wn + in * 16 + r;
    const float bv = bc1[col];
    const float w0 = Wc2[col * 2 + 0];
    const float w1 = Wc2[col * 2 + 1];
#pragma unroll
    for (int im = 0; im < 4; ++im)
#pragma unroll
      for (int rr = 0; rr < 4; ++rr) {
        float z = fmaxf(acc[im][in][rr] + bv, 0.f);
        p0[im * 4 + rr] += z * w0;
        p1[im * 4 + rr] += z * w1;
      }
  }
#pragma unroll
  for (int o2 = 1; o2 < 16; o2 <<= 1) {
#pragma unroll
    for (int k = 0; k < 16; ++k) {
      p0[k] += __shfl_xor(p0[k], o2);
      p1[k] += __shfl_xor(p1[k], o2);
    }
  }
  if (r == 0) {
#pragma unroll
    for (int im = 0; im < 4; ++im)
#pragma unroll
      for (int rr = 0; rr < 4; ++rr) {
        int row = bm + wm + im * 16 + q * 4 + rr;
        if (row < N_NODES) {
          atomicAdd(out + (size_t)row * 2,     p0[im * 4 + rr]);
          atomicAdd(out + (size_t)row * 2 + 1, p1[im * 4 + rr]);
        }
      }
  }
}

// ---------------------------------------------------------------------------
// Fused segment-softmax + aggregation + bias + LayerNorm + ELU.
// EXACT round-3 structure (measured 155 us): two-phase chunked edge loop with
// explicit load hoisting -- per 16-edge chunk: (1) ssc score-gather, (2) all
// 16 h8 row loads into a statically-indexed register array (scalar row base
// via readlane + shared lane*8 voffset), (3) next-chunk csr prefetch,
// (4) score chain, (5) accumulate. Rounds 2 (no hoist) and 4 (2-deep
// ping-pong, VGPR 64, occ 40%) both measured SLOWER -- do not restructure.
// h8 decode mapping identical to round 1 (channel = cbase + 16*(k&3)+(k>>2)).
// ---------------------------------------------------------------------------
__global__ __launch_bounds__(256) void k_aggregate(const unsigned char* __restrict__ h8,
                                                   const float2* __restrict__ ssc,
                                                   const int* __restrict__ csr_src,
                                                   const int* __restrict__ off,
                                                   const int* __restrict__ deg,
                                                   const float* __restrict__ s_dst,
                                                   const float* __restrict__ bvec,
                                                   const float* __restrict__ gvec,
                                                   const float* __restrict__ bevec,
                                                   unsigned short* __restrict__ out) {
  int node = blockIdx.x * 4 + (threadIdx.x >> 6);
  int lane = threadIdx.x & 63;
  if (node >= N_NODES) return;
  const int o   = __builtin_amdgcn_readfirstlane(off[node]);
  const int cnt = __builtin_amdgcn_readfirstlane(deg[node]);
  const int head = lane >> 4;
  const int li   = lane & 15;
  const int cbase = head * 128 + ((li & 8) ? 64 : 0) + ((2 * li) & 15);
  const float sdH = s_dst[(size_t)node * 4 + head];

  // acc2[k] = (channel cbase+16k [wx byte k], channel cbase+16k+1 [wy byte k])
  floatx2 acc2[4] = {};
  float sumP = 0.f, sumPS = 0.f;

  int base = 0;
  if (cnt >= 16) {
    int srcl = csr_src[o + li];                    // chunk 0 sources
    for (; base + 16 <= cnt; base += 16) {
      // (1) score gather FIRST (vmcnt-ordered ahead of the row loads)
      float2 fc = ssc[(size_t)srcl * 4 + head];
      // (2) hoist all 16 row loads into registers (static indices)
      uint2 rows[16];
#pragma unroll
      for (int j = 0; j < 16; ++j) {
        int sj = __builtin_amdgcn_readlane(srcl, j);
        rows[j] = *(const uint2*)(h8 + (size_t)sj * 512 + lane * 8);
      }
      // (3) prefetch next chunk's sources
      int srcl_next = srcl;
      if (base + 32 <= cnt) srcl_next = csr_src[o + base + 16 + li];
      // (4) score chain (waits only on fc)
      float e = fc.x + sdH;
      e = (e > 0.f) ? e : NEG_SLOPE * e;
      float p  = __expf(e);
      float ps = p * fc.y;
      sumP += p; sumPS += ps;
      // (5) accumulate
#pragma unroll
      for (int j = 0; j < 16; ++j) {
        float psj = __shfl(ps, j, 16);
        uint2 w = rows[j];
        floatx2 vp = {psj, psj};
        floatx2 b0 = {(float)( w.x        & 255u), (float)( w.y        & 255u)};
        floatx2 b1 = {(float)((w.x >>  8) & 255u), (float)((w.y >>  8) & 255u)};
        floatx2 b2 = {(float)((w.x >> 16) & 255u), (float)((w.y >> 16) & 255u)};
        floatx2 b3 = {(float)( w.x >> 24        ), (float)( w.y >> 24        )};
        acc2[0] += vp * b0;
        acc2[1] += vp * b1;
        acc2[2] += vp * b2;
        acc2[3] += vp * b3;
      }
      srcl = srcl_next;
    }
  }
  // ---- tail chunk (1..15 edges; >=1 guaranteed by self-loop when cnt<16) ----
  int m = cnt - base;
  if (m > 0) {
    int   idx  = (li < m) ? li : (m - 1);          // clamp: stay in-range
    int   srcl = csr_src[o + base + idx];
    float2 fc  = ssc[(size_t)srcl * 4 + head];
    uint2 rows[16];
#pragma unroll
    for (int j = 0; j < 16; ++j) {
      if (j < m) {                                  // wave-uniform predicate
        int sj = __builtin_amdgcn_readlane(srcl, j);
        rows[j] = *(const uint2*)(h8 + (size_t)sj * 512 + lane * 8);
      }
    }
    float e = fc.x + sdH;
    e = (e > 0.f) ? e : NEG_SLOPE * e;
    float p  = (li < m) ? __expf(e) : 0.f;
    float ps = p * fc.y;
    sumP += p; sumPS += ps;
#pragma unroll
    for (int j = 0; j < 16; ++j) {
      if (j < m) {
        float psj = __shfl(ps, j, 16);
        uint2 w = rows[j];
        floatx2 vp = {psj, psj};
        floatx2 b0 = {(float)( w.x        & 255u), (float)( w.y        & 255u)};
        floatx2 b1 = {(float)((w.x >>  8) & 255u), (float)((w.y >>  8) & 255u)};
        floatx2 b2 = {(float)((w.x >> 16) & 255u), (float)((w.y >> 16) & 255u)};
        floatx2 b3 = {(float)( w.x >> 24        ), (float)( w.y >> 24        )};
        acc2[0] += vp * b0;
        acc2[1] += vp * b1;
        acc2[2] += vp * b2;
        acc2[3] += vp * b3;
      }
    }
  }

  // reduce per-lane score partials across the 16-lane head group
#pragma unroll
  for (int o2 = 1; o2 < 16; o2 <<= 1) {
    sumP  += __shfl_xor(sumP,  o2);
    sumPS += __shfl_xor(sumPS, o2);
  }

  float acc[8];
#pragma unroll
  for (int k = 0; k < 4; ++k) { acc[k] = acc2[k].x; acc[k + 4] = acc2[k].y; }

  const float inv = 1.f / sumP;
  float bl[8];
#pragma unroll
  for (int k = 0; k < 4; ++k) {
    float2 v2 = *(const float2*)(bvec + cbase + 16 * k);
    bl[k] = v2.x; bl[k + 4] = v2.y;
  }
#pragma unroll
  for (int k = 0; k < 8; ++k)
    acc[k] = (acc[k] - 128.f * sumPS) * inv + bl[k];

  float ps2 = 0.f, pq = 0.f;
#pragma unroll
  for (int k = 0; k < 8; ++k) { ps2 += acc[k]; pq += acc[k]*acc[k]; }
#pragma unroll
  for (int o2 = 1; o2 < 64; o2 <<= 1) {
    ps2 += __shfl_xor(ps2, o2);
    pq  += __shfl_xor(pq, o2);
  }
  float mu  = ps2 * (1.f/512.f);
  float var = pq * (1.f/512.f) - mu*mu;
  float rstd = rsqrtf(var + LN_EPS);

  float gs[8], es[8];
#pragma unroll
  for (int k = 0; k < 4; ++k) {
    float2 g2 = *(const float2*)(gvec  + cbase + 16 * k);
    float2 e2 = *(const float2*)(bevec + cbase + 16 * k);
    gs[k] = g2.x; gs[k + 4] = g2.y;
    es[k] = e2.x; es[k + 4] = e2.y;
  }

  unsigned short us[8];
#pragma unroll
  for (int k = 0; k < 8; ++k) {
    float y = (acc[k] - mu) * rstd * gs[k] + es[k];
    y = (y > 0.f) ? y : expm1f(y);
    us[k] = f2bf(y);
  }
#pragma unroll
  for (int k = 0; k < 4; ++k) {
    unsigned int wv2 = (unsigned int)us[k] | ((unsigned int)us[k + 4] << 16);
    *(unsigned int*)(out + (size_t)node * D + cbase + 16 * k) = wv2;
  }
}

// ---------------------------------------------------------------------------
extern "C" void kernel_launch(void* const* d_in, const int* in_sizes, int n_in,
                              void* d_out, int out_size, void* d_ws, size_t ws_size,
                              hipStream_t stream) {
  const float* x      = (const float*)d_in[0];
  const int*   ei     = (const int*)  d_in[1];
  const float* W1     = (const float*)d_in[2];
  const float* a_src1 = (const float*)d_in[3];
  const float* a_dst1 = (const float*)d_in[4];
  const float* b1     = (const float*)d_in[5];
  const float* g1     = (const float*)d_in[6];
  const float* be1    = (const float*)d_in[7];
  const float* W2     = (const float*)d_in[8];
  const float* a_src2 = (const float*)d_in[9];
  const float* a_dst2 = (const float*)d_in[10];
  const float* b2     = (const float*)d_in[11];
  const float* g2     = (const float*)d_in[12];
  const float* be2    = (const float*)d_in[13];
  const float* Wc1    = (const float*)d_in[14];
  const float* bc1    = (const float*)d_in[15];
  const float* Wc2    = (const float*)d_in[16];
  const float* bc2    = (const float*)d_in[17];
  float* outp = (float*)d_out;

  char* p = (char*)d_ws;
  auto alloc = [&](size_t bytes) {
    char* r = p;
    p += (bytes + 255) & ~(size_t)255;
    return r;
  };
  unsigned short* obuf = (unsigned short*)alloc((size_t)M_PAD * D * 2); // 102.5 MB
  unsigned short* w1t  = (unsigned short*)alloc((size_t)512 * K1P * 2);
  unsigned short* w2t  = (unsigned short*)alloc((size_t)512 * 512 * 2);
  unsigned short* wc1t = (unsigned short*)alloc((size_t)512 * 512 * 2);
  int*   csr_src = (int*)  alloc((size_t)E_TOT * 4);                    // 6.8 MB
  int*   deg     = (int*)  alloc((size_t)N_NODES * 4);
  int*   off     = (int*)  alloc((size_t)N_NODES * 4);
  int*   pos     = (int*)  alloc((size_t)N_NODES * 4);
  int*   counter = (int*)  alloc(256);
  int*   flag    = (int*)  alloc(256);
  float2* ssc    = (float2*)alloc((size_t)N_NODES * 4 * 8);             // 3.2 MB
  float* s_dst   = (float*)alloc((size_t)N_NODES * 4 * 4);              // 1.6 MB
  unsigned char* h8 = (unsigned char*)alloc((size_t)M_PAD * 512);       // 51.2 MB
  // total ~= 168 MB (hbuf eliminated by the fused GEMM+sdots epilogue)
  // xb aliases obuf (dead after GEMM-1's A-reads, then overwritten by agg-1)
  unsigned short* xb = obuf;

  const int EB = (E_TOT + 255) / 256;
  const int NB = (N_NODES + 255) / 256;
  const int NW = (N_NODES + 3) / 4;
  dim3 gg(4, M_PAD / 128);

  // init (+fused dtype probe) + CSR build + weight conversion
  k_init  <<<NB, 256, 0, stream>>>(ei, deg, counter, flag);
  k_count <<<EB, 256, 0, stream>>>(ei, flag, deg);
  k_alloc <<<NB, 256, 0, stream>>>(deg, off, pos, counter);
  k_fill  <<<EB, 256, 0, stream>>>(ei, flag, pos, csr_src);

  k_cvt_x <<<(N_NODES * K1P + 255) / 256, 256, 0, stream>>>(x, xb);
  k_cvt_wt<<<(512 * K1P + 255) / 256, 256, 0, stream>>>(W1, w1t, FIN, K1P);
  k_cvt_wt<<<(512 * 512 + 255) / 256, 256, 0, stream>>>(W2, w2t, 512, 512);
  k_cvt_wt<<<(512 * 512 + 255) / 256, 256, 0, stream>>>(Wc1, wc1t, 512, 512);
  k_out_init<<<NB, 256, 0, stream>>>(bc2, outp);

  // Layer 1 (GEMM writes h8/ssc/s_dst directly; no bf16 h round-trip)
  gemm_fused <<<gg, 256, 0, stream>>>(xb, w1t, a_src1, a_dst1, ssc, s_dst, h8, K1P);
  k_aggregate<<<NW, 256, 0, stream>>>(h8, ssc, csr_src, off, deg,
                                      s_dst, b1, g1, be1, obuf);

  // Layer 2
  gemm_fused <<<gg, 256, 0, stream>>>(obuf, w2t, a_src2, a_dst2, ssc, s_dst, h8, 512);
  k_aggregate<<<NW, 256, 0, stream>>>(h8, ssc, csr_src, off, deg,
                                      s_dst, b2, g2, be2, obuf);

  // Classifier (fused relu + @Wc2 + bc2 via atomics)
  gemm_cls   <<<gg, 256, 0, stream>>>(obuf, wc1t, bc1, Wc2, outp, 512);
}